// Round 1
// baseline (186.460 us; speedup 1.0000x reference)
//
#include <hip/hip_runtime.h>

constexpr int B = 32;
constexpr int N = 32 * 32 * 32 + 1;   // 32769
constexpr int K = 32 * 3 * 3;         // 288

// ---------------------------------------------------------------------------
// Kernel 1: transpose x (B,N) -> xT (N,B). 32x32 tiles via LDS.
// ---------------------------------------------------------------------------
__global__ __launch_bounds__(256) void transpose_x_kernel(
    const float* __restrict__ x, float* __restrict__ xT) {
  __shared__ float tile[32][33];
  const int n0 = blockIdx.x * 32;
  const int t  = threadIdx.x;
  const int lb = t & 31;   // 0..31
  const int lr = t >> 5;   // 0..7
#pragma unroll
  for (int i = 0; i < 4; ++i) {
    const int b = lr + i * 8;
    const int n = n0 + lb;
    float v = 0.f;
    if (n < N) v = x[(size_t)b * N + n];   // coalesced over lb
    tile[lb][b] = v;
  }
  __syncthreads();
#pragma unroll
  for (int i = 0; i < 4; ++i) {
    const int nl = lr + i * 8;
    const int n  = n0 + nl;
    if (n < N) xT[(size_t)n * B + lb] = tile[nl][lb];  // coalesced over lb
  }
}

// ---------------------------------------------------------------------------
// Kernel 2: main gather-dot. yT[n][b] = sum_k xT[cols[n,k]][b] * vals[n,k]
// Mapping: 8-lane group per n; lane owns 4 consecutive b (float4 of xT row).
// 32 n per 256-thread block.
// ---------------------------------------------------------------------------
__global__ __launch_bounds__(256) void gather_dot_kernel(
    const float* __restrict__ xT, const float* __restrict__ vals,
    const int* __restrict__ cols, float* __restrict__ yT) {
  const int t    = threadIdx.x;
  const int lane = t & 63;
  const int wave = t >> 6;
  const int g    = lane >> 3;        // 0..7 : n within wave
  const int bq   = lane & 7;         // 0..7 : b quad -> b = 4*bq .. 4*bq+3
  const int n    = blockIdx.x * 32 + wave * 8 + g;
  if (n >= N) return;

  const int*   __restrict__ crow = cols + (size_t)n * K;
  const float* __restrict__ vrow = vals + (size_t)n * K;

  float4 acc = make_float4(0.f, 0.f, 0.f, 0.f);

#pragma unroll 4
  for (int k = 0; k < K; k += 4) {
    const int4   c4 = *reinterpret_cast<const int4*>(crow + k);
    const float4 v4 = *reinterpret_cast<const float4*>(vrow + k);

    const float4 x0 = *reinterpret_cast<const float4*>(xT + (size_t)c4.x * B + bq * 4);
    const float4 x1 = *reinterpret_cast<const float4*>(xT + (size_t)c4.y * B + bq * 4);
    const float4 x2 = *reinterpret_cast<const float4*>(xT + (size_t)c4.z * B + bq * 4);
    const float4 x3 = *reinterpret_cast<const float4*>(xT + (size_t)c4.w * B + bq * 4);

    acc.x += x0.x * v4.x; acc.y += x0.y * v4.x; acc.z += x0.z * v4.x; acc.w += x0.w * v4.x;
    acc.x += x1.x * v4.y; acc.y += x1.y * v4.y; acc.z += x1.z * v4.y; acc.w += x1.w * v4.y;
    acc.x += x2.x * v4.z; acc.y += x2.y * v4.z; acc.z += x2.z * v4.z; acc.w += x2.w * v4.z;
    acc.x += x3.x * v4.w; acc.y += x3.y * v4.w; acc.z += x3.z * v4.w; acc.w += x3.w * v4.w;
  }

  *reinterpret_cast<float4*>(yT + (size_t)n * B + bq * 4) = acc;
}

// ---------------------------------------------------------------------------
// Kernel 3: transpose yT (N,B) -> y (B,N).
// ---------------------------------------------------------------------------
__global__ __launch_bounds__(256) void transpose_y_kernel(
    const float* __restrict__ yT, float* __restrict__ y) {
  __shared__ float tile[32][33];
  const int n0 = blockIdx.x * 32;
  const int t  = threadIdx.x;
  const int lb = t & 31;
  const int lr = t >> 5;
#pragma unroll
  for (int i = 0; i < 4; ++i) {
    const int nl = lr + i * 8;
    const int n  = n0 + nl;
    float v = 0.f;
    if (n < N) v = yT[(size_t)n * B + lb];   // coalesced over lb
    tile[nl][lb] = v;
  }
  __syncthreads();
#pragma unroll
  for (int i = 0; i < 4; ++i) {
    const int b = lr + i * 8;
    const int n = n0 + lb;
    if (n < N) y[(size_t)b * N + n] = tile[lb][b];  // coalesced over lb
  }
}

// ---------------------------------------------------------------------------
// Fallback (ws too small): direct strided gather, correct but slow.
// ---------------------------------------------------------------------------
__global__ __launch_bounds__(256) void gather_dot_fallback(
    const float* __restrict__ x, const float* __restrict__ vals,
    const int* __restrict__ cols, float* __restrict__ y) {
  const int t    = threadIdx.x;
  const int lane = t & 63;
  const int wave = t >> 6;
  const int g    = lane >> 3;
  const int bq   = lane & 7;
  const int n    = blockIdx.x * 32 + wave * 8 + g;
  if (n >= N) return;
  const int*   crow = cols + (size_t)n * K;
  const float* vrow = vals + (size_t)n * K;
  float4 acc = make_float4(0.f, 0.f, 0.f, 0.f);
  for (int k = 0; k < K; ++k) {
    const int   c = crow[k];
    const float v = vrow[k];
    acc.x += x[(size_t)(bq * 4 + 0) * N + c] * v;
    acc.y += x[(size_t)(bq * 4 + 1) * N + c] * v;
    acc.z += x[(size_t)(bq * 4 + 2) * N + c] * v;
    acc.w += x[(size_t)(bq * 4 + 3) * N + c] * v;
  }
  y[(size_t)(bq * 4 + 0) * N + n] = acc.x;
  y[(size_t)(bq * 4 + 1) * N + n] = acc.y;
  y[(size_t)(bq * 4 + 2) * N + n] = acc.z;
  y[(size_t)(bq * 4 + 3) * N + n] = acc.w;
}

extern "C" void kernel_launch(void* const* d_in, const int* in_sizes, int n_in,
                              void* d_out, int out_size, void* d_ws, size_t ws_size,
                              hipStream_t stream) {
  const float* x    = (const float*)d_in[0];   // x_affine (B,N)
  const float* vals = (const float*)d_in[1];   // (N,K)
  const int*   cols = (const int*)d_in[2];     // (N,K)
  float*       y    = (float*)d_out;           // (B,N)

  const size_t xT_elems = (size_t)N * B;                 // 4.19 MB
  const size_t need     = 2 * xT_elems * sizeof(float);  // xT + yT

  const int nblocks = (N + 31) / 32;   // 1025

  if (ws_size >= need) {
    float* xT = (float*)d_ws;
    float* yT = xT + xT_elems;
    transpose_x_kernel<<<nblocks, 256, 0, stream>>>(x, xT);
    gather_dot_kernel<<<nblocks, 256, 0, stream>>>(xT, vals, cols, yT);
    transpose_y_kernel<<<nblocks, 256, 0, stream>>>(yT, y);
  } else {
    gather_dot_fallback<<<nblocks, 256, 0, stream>>>(x, vals, cols, y);
  }
}